// Round 1
// 307.891 us; speedup vs baseline: 1.0512x; 1.0512x over previous
//
#include <hip/hip_runtime.h>

#define B 32
#define C 512
#define TP 1024
#define CHUNK 16
#define RMAX 432   // staged phone range cap (dwords); typ. need ~296, +12 sigma safe
#define TTILE 1024

typedef float f4 __attribute__((ext_vector_type(4)));

// searchsorted(s, t, side='right') over TP entries
__device__ __forceinline__ int srch_right(const int* s, int t) {
    int lo = 0, hi = TP;
    while (lo < hi) {
        int mid = (lo + hi) >> 1;
        if (s[mid] <= t) lo = mid + 1; else hi = mid;
    }
    return lo;
}

// Single fused kernel: per-block cumsum of durations (redundant but parallel),
// uniform phone-range computation, LDS staging of the x slice (coalesced f4
// reads), LDS gather + NT f4 stores. Fallback to direct-global gather if the
// block's phone range exceeds RMAX (correctness; ~never taken for this data).
template <bool VEC>
__global__ void __launch_bounds__(256) lenreg_k(
        const float* __restrict__ x, const int* __restrict__ dur,
        float* __restrict__ out, float* __restrict__ mask, int MF) {
    __shared__ int scum[TP];
    __shared__ float xs[CHUNK][RMAX];
    __shared__ int wtot[4];

    const int tid = threadIdx.x, lane = tid & 63, wid = tid >> 6;
    const int b = blockIdx.y, z = blockIdx.z;

    // ---- fused inclusive cumsum of dur[b][0..1023] into scum ----
    int4 d4 = ((const int4*)(dur + b * TP))[tid];
    const int s1 = d4.x + d4.y, s2 = s1 + d4.z, s3 = s2 + d4.w;
    int v = s3;
    #pragma unroll
    for (int off = 1; off < 64; off <<= 1) {
        int n = __shfl_up(v, off, 64);
        if (lane >= off) v += n;
    }
    if (lane == 63) wtot[wid] = v;
    __syncthreads();
    int bse = 0;
    #pragma unroll
    for (int w = 0; w < 4; ++w) if (w < wid) bse += wtot[w];
    const int excl = bse + v - s3;
    int4 o; o.x = excl + d4.x; o.y = excl + s1; o.z = excl + s2; o.w = excl + s3;
    ((int4*)scum)[tid] = o;
    __syncthreads();

    const int total = scum[TP - 1];
    const int tb0 = blockIdx.x * TTILE;
    const bool blk_valid = total > tb0;   // any valid frame in this t-tile?

    // ---- block-uniform phone range for staging ----
    int p0a = 0, Ra = 0;
    bool stage = false;
    if (blk_valid) {
        const int t_hi = min(min(tb0 + TTILE, total), MF) - 1;  // last valid t
        const int p_lo = srch_right(scum, tb0);
        const int p_hi = srch_right(scum, t_hi);
        p0a = p_lo & ~3;                  // align down for f4 staging loads
        Ra = p_hi - p0a + 1;
        stage = (Ra <= RMAX);
    }

    const float* xb = x + ((size_t)b * C + (size_t)z * CHUNK) * TP;

    // ---- issue staging loads (coalesced f4), sync deferred past the search ----
    if (stage) {
        const int nf4 = (Ra + 3) >> 2;    // <= 108
        #pragma unroll
        for (int rr = 0; rr < CHUNK / 4; ++rr) {
            const int r = rr * 4 + wid;   // one row per wave per pass
            const float* xr = xb + (size_t)r * TP + p0a;
            for (int i = lane; i < nf4; i += 64) {
                f4 t4 = ((const f4*)xr)[i];
                *((f4*)&xs[r][i * 4]) = t4;
            }
        }
    }

    const int t0 = tb0 + tid * 4;
    const bool active = t0 < MF;
    const bool full = VEC && (t0 + 4 <= MF);

    // ---- per-thread search + mask (overlaps with staging latency) ----
    int q[4]; bool vld[4]; int ix[4];
    if (active) {
        if (blk_valid) {
            int pc = srch_right(scum, t0);
            #pragma unroll
            for (int j = 0; j < 4; ++j) {
                const int tj = t0 + j;
                while (pc < TP && scum[pc] <= tj) ++pc;
                q[j] = pc < TP - 1 ? pc : TP - 1;
                vld[j] = (tj < total) && (tj < MF);
                ix[j] = vld[j] ? q[j] - p0a : 0;  // always in [0, Ra)
            }
        } else {
            #pragma unroll
            for (int j = 0; j < 4; ++j) { q[j] = TP - 1; vld[j] = false; ix[j] = 0; }
        }
        if (z == 0) {  // mel_mask = (t >= total)
            float m[4];
            #pragma unroll
            for (int j = 0; j < 4; ++j) m[j] = (t0 + j < total) ? 0.0f : 1.0f;
            float* mrow = mask + (size_t)b * MF + t0;
            if (full) {
                f4 mv = {m[0], m[1], m[2], m[3]};
                __builtin_nontemporal_store(mv, (f4*)mrow);
            } else {
                #pragma unroll
                for (int j = 0; j < 4; ++j)
                    if (t0 + j < MF) __builtin_nontemporal_store(m[j], mrow + j);
            }
        }
    }

    if (stage) __syncthreads();
    if (!active) return;

    float* ob = out + ((size_t)b * C + (size_t)z * CHUNK) * MF;

    if (!blk_valid) {  // whole tile past total: pure zero writes, no loads
        const f4 zz = {0.0f, 0.0f, 0.0f, 0.0f};
        #pragma unroll 4
        for (int c = 0; c < CHUNK; ++c) {
            float* orow = ob + (size_t)c * MF + t0;
            if (full) {
                __builtin_nontemporal_store(zz, (f4*)orow);
            } else {
                #pragma unroll
                for (int j = 0; j < 4; ++j)
                    if (t0 + j < MF) __builtin_nontemporal_store(0.0f, orow + j);
            }
        }
        return;
    }

    if (stage) {
        // gathers served from LDS (parallel pipe to the NT stores)
        #pragma unroll 2
        for (int c = 0; c < CHUNK; ++c) {
            float l0 = xs[c][ix[0]], l1 = xs[c][ix[1]],
                  l2 = xs[c][ix[2]], l3 = xs[c][ix[3]];
            f4 v4;
            v4.x = vld[0] ? l0 : 0.0f;
            v4.y = vld[1] ? l1 : 0.0f;
            v4.z = vld[2] ? l2 : 0.0f;
            v4.w = vld[3] ? l3 : 0.0f;
            float* orow = ob + (size_t)c * MF + t0;
            if (full) {
                __builtin_nontemporal_store(v4, (f4*)orow);
            } else {
                const float vv[4] = {v4.x, v4.y, v4.z, v4.w};
                #pragma unroll
                for (int j = 0; j < 4; ++j)
                    if (t0 + j < MF) __builtin_nontemporal_store(vv[j], orow + j);
            }
        }
    } else {
        // fallback: direct-global gather (phone range too wide to stage)
        #pragma unroll 2
        for (int c = 0; c < CHUNK; ++c) {
            const float* xr = xb + (size_t)c * TP;
            float l0 = xr[q[0]], l1 = xr[q[1]], l2 = xr[q[2]], l3 = xr[q[3]];
            f4 v4;
            v4.x = vld[0] ? l0 : 0.0f;
            v4.y = vld[1] ? l1 : 0.0f;
            v4.z = vld[2] ? l2 : 0.0f;
            v4.w = vld[3] ? l3 : 0.0f;
            float* orow = ob + (size_t)c * MF + t0;
            if (full) {
                __builtin_nontemporal_store(v4, (f4*)orow);
            } else {
                const float vv[4] = {v4.x, v4.y, v4.z, v4.w};
                #pragma unroll
                for (int j = 0; j < 4; ++j)
                    if (t0 + j < MF) __builtin_nontemporal_store(vv[j], orow + j);
            }
        }
    }
}

extern "C" void kernel_launch(void* const* d_in, const int* in_sizes, int n_in,
                              void* d_out, int out_size, void* d_ws, size_t ws_size,
                              hipStream_t stream) {
    const float* x   = (const float*)d_in[0];
    const int*   dur = (const int*)d_in[1];
    float* out = (float*)d_out;

    // out_size in elements = B*(C+1)*MF
    const int MF = out_size / (B * (C + 1));
    float* mask = out + (size_t)B * C * MF;

    dim3 g((MF + TTILE - 1) / TTILE, B, C / CHUNK);
    if ((MF & 3) == 0)
        lenreg_k<true><<<g, 256, 0, stream>>>(x, dur, out, mask, MF);
    else
        lenreg_k<false><<<g, 256, 0, stream>>>(x, dur, out, mask, MF);
}

// Round 2
// 307.528 us; speedup vs baseline: 1.0524x; 1.0012x over previous
//
#include <hip/hip_runtime.h>

#define B 32
#define C 512
#define TP 1024
#define CHUNK 16
#define RMAX 352   // staged range cap; mean need ~299, sigma ~11 -> +4.6 sigma; 6 blocks/CU
#define TTILE 1024

typedef float f4 __attribute__((ext_vector_type(4)));

// searchsorted(s, t, side='right') over [lo, hi)
__device__ __forceinline__ int srch_right(const int* s, int t, int lo, int hi) {
    while (lo < hi) {
        int mid = (lo + hi) >> 1;
        if (s[mid] <= t) lo = mid + 1; else hi = mid;
    }
    return lo;
}

// Fused: per-block cumsum (redundant, parallel), block-uniform phone range,
// LDS staging of the x slice (coalesced f4), zero-slot gather (no cndmask),
// NT f4 stores. Fallback to direct-global gather if range > RMAX (correctness).
template <bool VEC>
__global__ void __launch_bounds__(256) lenreg_k(
        const float* __restrict__ x, const int* __restrict__ dur,
        float* __restrict__ out, float* __restrict__ mask, int MF) {
    __shared__ int scum[TP];
    __shared__ float xs[CHUNK][RMAX];
    __shared__ int wtot[4];

    const int tid = threadIdx.x, lane = tid & 63, wid = tid >> 6;
    const int b = blockIdx.y, z = blockIdx.z;

    // ---- fused inclusive cumsum of dur[b][0..1023] into scum ----
    int4 d4 = ((const int4*)(dur + b * TP))[tid];
    const int s1 = d4.x + d4.y, s2 = s1 + d4.z, s3 = s2 + d4.w;
    int v = s3;
    #pragma unroll
    for (int off = 1; off < 64; off <<= 1) {
        int n = __shfl_up(v, off, 64);
        if (lane >= off) v += n;
    }
    if (lane == 63) wtot[wid] = v;
    __syncthreads();
    int bse = 0;
    #pragma unroll
    for (int w = 0; w < 4; ++w) if (w < wid) bse += wtot[w];
    const int excl = bse + v - s3;
    int4 o; o.x = excl + d4.x; o.y = excl + s1; o.z = excl + s2; o.w = excl + s3;
    ((int4*)scum)[tid] = o;
    __syncthreads();

    const int total = scum[TP - 1];
    const int tb0 = blockIdx.x * TTILE;
    const bool blk_valid = total > tb0;

    // ---- block-uniform phone window ----
    int p_lo = 0, p_hi = TP - 1, p0a = 0, Ra = 0;
    bool stage = false;
    if (blk_valid) {
        const int t_hi = min(min(tb0 + TTILE, total), MF) - 1;  // last valid t
        p_lo = srch_right(scum, tb0, 0, TP);
        p_hi = srch_right(scum, t_hi, p_lo, TP);
        p0a = p_lo & ~3;                 // align down for f4 staging
        Ra = p_hi - p0a + 1;
        stage = (Ra < RMAX);             // strict: slot RMAX-1 reserved as zero
    }

    const float* xb = x + ((size_t)b * C + (size_t)z * CHUNK) * TP;

    // ---- issue staging loads (coalesced f4); sync deferred past the search ----
    if (stage) {
        const int nf4 = (Ra + 3) >> 2;   // <= 88; never reads past row end
        #pragma unroll
        for (int rr = 0; rr < CHUNK / 4; ++rr) {
            const int r = rr * 4 + wid;  // one row per wave per pass
            const float* xr = xb + (size_t)r * TP + p0a;
            for (int i = lane; i < nf4; i += 64) {
                f4 t4 = ((const f4*)xr)[i];
                *((f4*)&xs[r][i * 4]) = t4;
            }
        }
        if (tid < CHUNK) xs[tid][RMAX - 1] = 0.0f;   // zero slot per row
    }

    const int t0 = tb0 + tid * 4;
    const bool active = t0 < MF;
    const bool full = VEC && (t0 + 4 <= MF);

    // ---- per-thread windowed search + mask (overlaps staging latency) ----
    int q[4]; bool vld[4]; int ix[4];
    if (active && blk_valid) {
        int pc = srch_right(scum, t0, p_lo, p_hi + 1);
        #pragma unroll
        for (int j = 0; j < 4; ++j) {
            const int tj = t0 + j;
            while (pc < TP && scum[pc] <= tj) ++pc;
            q[j] = pc < TP - 1 ? pc : TP - 1;
            vld[j] = (tj < total) && (tj < MF);
            ix[j] = vld[j] ? q[j] - p0a : RMAX - 1;   // invalid -> zero slot
        }
    } else {
        #pragma unroll
        for (int j = 0; j < 4; ++j) { q[j] = TP - 1; vld[j] = false; ix[j] = RMAX - 1; }
    }

    if (active && z == 0) {  // mel_mask = (t >= total)
        float m[4];
        #pragma unroll
        for (int j = 0; j < 4; ++j) m[j] = (t0 + j < total) ? 0.0f : 1.0f;
        float* mrow = mask + (size_t)b * MF + t0;
        if (full) {
            f4 mv = {m[0], m[1], m[2], m[3]};
            __builtin_nontemporal_store(mv, (f4*)mrow);
        } else {
            #pragma unroll
            for (int j = 0; j < 4; ++j)
                if (t0 + j < MF) __builtin_nontemporal_store(m[j], mrow + j);
        }
    }

    if (stage) __syncthreads();
    if (!active) return;

    float* ob = out + ((size_t)b * C + (size_t)z * CHUNK) * MF;

    if (!blk_valid) {  // whole tile past total: pure zero writes, no loads
        const f4 zz = {0.0f, 0.0f, 0.0f, 0.0f};
        #pragma unroll 4
        for (int c = 0; c < CHUNK; ++c) {
            float* orow = ob + (size_t)c * MF + t0;
            if (full) {
                __builtin_nontemporal_store(zz, (f4*)orow);
            } else {
                #pragma unroll
                for (int j = 0; j < 4; ++j)
                    if (t0 + j < MF) __builtin_nontemporal_store(0.0f, orow + j);
            }
        }
        return;
    }

    if (stage) {
        // zero-slot gather from LDS: 4 ds_read + 1 NT store per c, no cndmask
        #pragma unroll 4
        for (int c = 0; c < CHUNK; ++c) {
            f4 v4;
            v4.x = xs[c][ix[0]];
            v4.y = xs[c][ix[1]];
            v4.z = xs[c][ix[2]];
            v4.w = xs[c][ix[3]];
            float* orow = ob + (size_t)c * MF + t0;
            if (full) {
                __builtin_nontemporal_store(v4, (f4*)orow);
            } else {
                const float vv[4] = {v4.x, v4.y, v4.z, v4.w};
                #pragma unroll
                for (int j = 0; j < 4; ++j)
                    if (t0 + j < MF) __builtin_nontemporal_store(vv[j], orow + j);
            }
        }
    } else {
        // fallback: direct-global gather (range too wide to stage)
        #pragma unroll 2
        for (int c = 0; c < CHUNK; ++c) {
            const float* xr = xb + (size_t)c * TP;
            float l0 = xr[q[0]], l1 = xr[q[1]], l2 = xr[q[2]], l3 = xr[q[3]];
            f4 v4;
            v4.x = vld[0] ? l0 : 0.0f;
            v4.y = vld[1] ? l1 : 0.0f;
            v4.z = vld[2] ? l2 : 0.0f;
            v4.w = vld[3] ? l3 : 0.0f;
            float* orow = ob + (size_t)c * MF + t0;
            if (full) {
                __builtin_nontemporal_store(v4, (f4*)orow);
            } else {
                const float vv[4] = {v4.x, v4.y, v4.z, v4.w};
                #pragma unroll
                for (int j = 0; j < 4; ++j)
                    if (t0 + j < MF) __builtin_nontemporal_store(vv[j], orow + j);
            }
        }
    }
}

extern "C" void kernel_launch(void* const* d_in, const int* in_sizes, int n_in,
                              void* d_out, int out_size, void* d_ws, size_t ws_size,
                              hipStream_t stream) {
    const float* x   = (const float*)d_in[0];
    const int*   dur = (const int*)d_in[1];
    float* out = (float*)d_out;

    // out_size in elements = B*(C+1)*MF
    const int MF = out_size / (B * (C + 1));
    float* mask = out + (size_t)B * C * MF;

    dim3 g((MF + TTILE - 1) / TTILE, B, C / CHUNK);
    if ((MF & 3) == 0)
        lenreg_k<true><<<g, 256, 0, stream>>>(x, dur, out, mask, MF);
    else
        lenreg_k<false><<<g, 256, 0, stream>>>(x, dur, out, mask, MF);
}